// Round 2
// baseline (556.021 us; speedup 1.0000x reference)
//
#include <hip/hip_runtime.h>
#include <hip/hip_bf16.h>

// dendriticNet fused kernel, round 1: latency-bound fix.
// R0 post-mortem: 239us main dispatch, 20% total pipe busy, occupancy 23% —
// per-block critical path (7 barriers x vmcnt(0) drains + L2-latency B loads)
// dominated. R1: BM=16, all 6 activations staged up front, ONE barrier,
// barrier-free GEMM/epilogue body, 2048 blocks, raw prefetch per phase,
// nontemporal output stores.
//
// Folding (unchanged, verified in R0):
//   out_s0 = 0.81*s0 + rd@(.1 wpf0)^T + rs1@(.08 wpb0)^T + ri0@(.08 wpi0)^T
//   out_i0 = 0.81*i0 + rs0@(.1 wip0)^T + 0.08*mean_row(rs1)
//   out_s1 = 0.81*s1 + rs0@(.1 wpf1)^T + rs2@(.08 wpb1)^T + ri1@(.08 wpi1)^T
//   out_i1 = 0.81*i1 + rs1@(.1 wip1)^T + 0.08*mean_row(rs2)
//   out_s2 = 0.89*s2 + rs1@(.1 wpf2)^T

#define HH 256
#define BM 16
#define ROWP 264                    // padded LDS row (bf16), 528 B: 16B-aligned, conflict-floor b128 reads
#define TILE_ELEMS (BM * ROWP)      // 4224 bf16 = 8448 B per tile
#define BHTOT ((size_t)32768 * 256)

typedef __bf16 bf16_t;
typedef __bf16 bf16x8 __attribute__((ext_vector_type(8)));
typedef float  f32x4  __attribute__((ext_vector_type(4)));

__device__ __forceinline__ float fast_tanh(float x) {
    float e = __expf(2.0f * x);
    return 1.0f - 2.0f * __builtin_amdgcn_rcpf(e + 1.0f);
}

// Stage one BM x 256 f32 tile -> tanh -> bf16 LDS tile (padded rows).
// Wave wv covers rows {wv, wv+4, wv+8, wv+12} fully (64 lanes x float4 = 256 cols),
// so the optional row-mean reduction is a pure wave shuffle.
__device__ __forceinline__ void stage_tile(const float* __restrict__ src,
                                           bf16_t* __restrict__ dst,
                                           int row0, int lane, int wv,
                                           float* __restrict__ nudge) {
#pragma unroll
    for (int it = 0; it < 4; ++it) {
        int row = wv + it * 4;
        const float4 v = *reinterpret_cast<const float4*>(
            src + (size_t)(row0 + row) * HH + lane * 4);
        float t0 = fast_tanh(v.x), t1 = fast_tanh(v.y);
        float t2 = fast_tanh(v.z), t3 = fast_tanh(v.w);
        union { bf16_t b[4]; unsigned long long u; } pk;
        pk.b[0] = (bf16_t)t0; pk.b[1] = (bf16_t)t1;
        pk.b[2] = (bf16_t)t2; pk.b[3] = (bf16_t)t3;
        *reinterpret_cast<unsigned long long*>(dst + row * ROWP + lane * 4) = pk.u;
        if (nudge) {
            float s = (t0 + t1) + (t2 + t3);
            s += __shfl_down(s, 32);
            s += __shfl_down(s, 16);
            s += __shfl_down(s, 8);
            s += __shfl_down(s, 4);
            s += __shfl_down(s, 2);
            s += __shfl_down(s, 1);
            if (lane == 0) nudge[row] = s * (0.08f / 256.0f);  // DT*GSOM*mean
        }
    }
}

// acc(16 x [64-col wave slice]) += rho_tile @ Wg^T, K=256.
// A-frag: A[m=lane&15][k=(lane>>4)*8+j]; B-frag: B[k][n=lane&15] (verified R0).
__device__ __forceinline__ void gemm_seg(const bf16_t* __restrict__ sa,
                                         const bf16_t* __restrict__ wg,
                                         int lane, int wv, f32x4 acc[4]) {
    const int r = lane & 15, q = lane >> 4;
    const bf16_t* ap = sa + r * ROWP + q * 8;
    const bf16_t* bp = wg + (size_t)(wv * 64 + r) * HH + q * 8;
#pragma unroll 4
    for (int k0 = 0; k0 < HH; k0 += 32) {
        bf16x8 a = *reinterpret_cast<const bf16x8*>(ap + k0);
#pragma unroll
        for (int nt = 0; nt < 4; ++nt) {
            bf16x8 b = *reinterpret_cast<const bf16x8*>(bp + nt * 16 * HH + k0);
            acc[nt] = __builtin_amdgcn_mfma_f32_16x16x32_bf16(a, b, acc[nt], 0, 0, 0);
        }
    }
}

// Prefetch c*raw contributions (C-frag layout) into registers BEFORE the GEMM
// chain of a phase, so the L2/L3 latency hides under MFMA.
__device__ __forceinline__ void load_raw(const float* __restrict__ raw,
                                         int row0, int lane, int wv,
                                         float rawv[16]) {
    const int cb = lane & 15, q = lane >> 4;
#pragma unroll
    for (int nt = 0; nt < 4; ++nt) {
        int col = wv * 64 + nt * 16 + cb;
#pragma unroll
        for (int rg = 0; rg < 4; ++rg) {
            int lrow = q * 4 + rg;
            rawv[nt * 4 + rg] = raw[(size_t)(row0 + lrow) * HH + col];
        }
    }
}

// out = acc + c*rawv (+ nudge[row]); nontemporal store (output never re-read;
// keep it out of L2 so raw re-reads stay cached).
__device__ __forceinline__ void epilogue(f32x4 acc[4], const float rawv[16],
                                         float* __restrict__ outp, int row0,
                                         int lane, int wv, float c,
                                         const float* __restrict__ nudge) {
    const int cb = lane & 15, q = lane >> 4;
#pragma unroll
    for (int nt = 0; nt < 4; ++nt) {
        int col = wv * 64 + nt * 16 + cb;
#pragma unroll
        for (int rg = 0; rg < 4; ++rg) {
            int lrow = q * 4 + rg;
            float v = acc[nt][rg] + c * rawv[nt * 4 + rg];
            if (nudge) v += nudge[lrow];
            __builtin_nontemporal_store(v, outp + (size_t)(row0 + lrow) * HH + col);
        }
    }
}

struct WPtrs { const float* p[9]; };

// Pre-scale + convert 9 weight matrices to bf16 in d_ws.
// g: 0 wpf0(.1) 1 wpf1(.1) 2 wpf2(.1) 3 wpb0(.08) 4 wpb1(.08)
//    5 wip0(.1) 6 wip1(.1) 7 wpi0(.08) 8 wpi1(.08)
__global__ void prep_w(WPtrs wp, bf16_t* __restrict__ out) {
    const float scales[9] = {0.1f, 0.1f, 0.1f, 0.08f, 0.08f, 0.1f, 0.1f, 0.08f, 0.08f};
    int g  = blockIdx.x >> 6;
    int bi = blockIdx.x & 63;
    float sc = scales[g];
    int idx = (bi * 256 + threadIdx.x) * 4;
    float4 v = *reinterpret_cast<const float4*>(wp.p[g] + idx);
    union { bf16_t b[4]; unsigned long long u; } pk;
    pk.b[0] = (bf16_t)(v.x * sc); pk.b[1] = (bf16_t)(v.y * sc);
    pk.b[2] = (bf16_t)(v.z * sc); pk.b[3] = (bf16_t)(v.w * sc);
    *reinterpret_cast<unsigned long long*>(out + (size_t)g * 65536 + idx) = pk.u;
}

__global__ __launch_bounds__(256) void dendritic_main(
    const float* __restrict__ data, const float* __restrict__ s0,
    const float* __restrict__ s1,   const float* __restrict__ s2,
    const float* __restrict__ i0,   const float* __restrict__ i1,
    const bf16_t* __restrict__ wws, float* __restrict__ out)
{
    extern __shared__ char smem[];
    bf16_t* t_rd  = (bf16_t*)smem;
    bf16_t* t_rs0 = t_rd  + TILE_ELEMS;
    bf16_t* t_rs1 = t_rs0 + TILE_ELEMS;
    bf16_t* t_rs2 = t_rs1 + TILE_ELEMS;
    bf16_t* t_ri0 = t_rs2 + TILE_ELEMS;
    bf16_t* t_ri1 = t_ri0 + TILE_ELEMS;
    float*  snudge = (float*)(t_ri1 + TILE_ELEMS);  // [2][16]

    const int tid = threadIdx.x, lane = tid & 63, wv = tid >> 6;
    const int row0 = blockIdx.x * BM;

    // ---- stage everything; 24 independent float4 HBM loads in flight ----
    stage_tile(data, t_rd,  row0, lane, wv, nullptr);
    stage_tile(s0,   t_rs0, row0, lane, wv, nullptr);
    stage_tile(s1,   t_rs1, row0, lane, wv, snudge);       // nudge0
    stage_tile(s2,   t_rs2, row0, lane, wv, snudge + 16);  // nudge1
    stage_tile(i0,   t_ri0, row0, lane, wv, nullptr);
    stage_tile(i1,   t_ri1, row0, lane, wv, nullptr);
    __syncthreads();   // the ONLY barrier — everything below is read-only LDS

    f32x4 acc[4];
    float rawv[16];
    const f32x4 z = {0.f, 0.f, 0.f, 0.f};

    // ---------- phase s0 -> out[0]
#pragma unroll
    for (int nt = 0; nt < 4; ++nt) acc[nt] = z;
    load_raw(s0, row0, lane, wv, rawv);
    gemm_seg(t_rd,  wws + 0 * 65536, lane, wv, acc);
    gemm_seg(t_rs1, wws + 3 * 65536, lane, wv, acc);
    gemm_seg(t_ri0, wws + 7 * 65536, lane, wv, acc);
    epilogue(acc, rawv, out + 0 * BHTOT, row0, lane, wv, 0.81f, nullptr);

    // ---------- phase i0 -> out[3]
#pragma unroll
    for (int nt = 0; nt < 4; ++nt) acc[nt] = z;
    load_raw(i0, row0, lane, wv, rawv);
    gemm_seg(t_rs0, wws + 5 * 65536, lane, wv, acc);
    epilogue(acc, rawv, out + 3 * BHTOT, row0, lane, wv, 0.81f, snudge);

    // ---------- phase s1 -> out[1]
#pragma unroll
    for (int nt = 0; nt < 4; ++nt) acc[nt] = z;
    load_raw(s1, row0, lane, wv, rawv);
    gemm_seg(t_rs0, wws + 1 * 65536, lane, wv, acc);
    gemm_seg(t_rs2, wws + 4 * 65536, lane, wv, acc);
    gemm_seg(t_ri1, wws + 8 * 65536, lane, wv, acc);
    epilogue(acc, rawv, out + 1 * BHTOT, row0, lane, wv, 0.81f, nullptr);

    // ---------- phase i1 -> out[4]
#pragma unroll
    for (int nt = 0; nt < 4; ++nt) acc[nt] = z;
    load_raw(i1, row0, lane, wv, rawv);
    gemm_seg(t_rs1, wws + 6 * 65536, lane, wv, acc);
    epilogue(acc, rawv, out + 4 * BHTOT, row0, lane, wv, 0.81f, snudge + 16);

    // ---------- phase s2 -> out[2]
#pragma unroll
    for (int nt = 0; nt < 4; ++nt) acc[nt] = z;
    load_raw(s2, row0, lane, wv, rawv);
    gemm_seg(t_rs1, wws + 2 * 65536, lane, wv, acc);
    epilogue(acc, rawv, out + 2 * BHTOT, row0, lane, wv, 0.89f, nullptr);
}

extern "C" void kernel_launch(void* const* d_in, const int* in_sizes, int n_in,
                              void* d_out, int out_size, void* d_ws, size_t ws_size,
                              hipStream_t stream) {
    const float* data = (const float*)d_in[0];
    const float* s0   = (const float*)d_in[1];
    const float* s1   = (const float*)d_in[2];
    const float* s2   = (const float*)d_in[3];
    const float* i0   = (const float*)d_in[4];
    const float* i1   = (const float*)d_in[5];

    WPtrs wp;
    for (int g = 0; g < 9; ++g) wp.p[g] = (const float*)d_in[6 + g];

    bf16_t* wws = (bf16_t*)d_ws;        // 9*65536*2 = 1,179,648 B scratch
    float*  out = (float*)d_out;

    prep_w<<<576, 256, 0, stream>>>(wp, wws);

    // 2048 blocks x 256 threads; LDS = 6 tiles + 2x16 nudge floats = 50,816 B
    const int ldsBytes = 6 * TILE_ELEMS * 2 + 2 * 16 * 4;
    dendritic_main<<<2048, 256, ldsBytes, stream>>>(data, s0, s1, s2, i0, i1, wws, out);
}